// Round 8
// baseline (1663.811 us; speedup 1.0000x reference)
//
#include <hip/hip_runtime.h>
#include <hip/hip_fp16.h>
#include <stdint.h>

// GCN 2-layer forward: dst-bucketed edges, src-tile-sorted within bucket,
// LDS-tile accumulation (layer1 + layer2). No global fp32 atomics, no CSR.
// Key idea: sorting each bucket's edge stream by src>>13 makes all concurrent
// blocks sweep h1w in the same ~512KB window -> random reads become L2 hits.

#define TPB 256
#define TILE 512           // dst nodes per bucket
#define TSH  9
#define MAXB 512           // supports N <= 262144 (src must fit 18 bits)
#define SRCSH 13           // src-tile shift: 8192 nodes = 512KB of h1w per tile

__global__ void k_zero_i(int* __restrict__ p, int m) {
    int i = blockIdx.x * TPB + threadIdx.x;
    if (i < m) p[i] = 0;
}

// global per-bucket histogram (LDS-staged)
__global__ __launch_bounds__(TPB) void k_bhist(const int* __restrict__ dst,
                                               int* __restrict__ bcnt, int e, int nb) {
    __shared__ int h[MAXB];
    for (int i = threadIdx.x; i < MAXB; i += TPB) h[i] = 0;
    __syncthreads();
    int stride = gridDim.x * TPB;
    for (int i = blockIdx.x * TPB + threadIdx.x; i < e; i += stride)
        atomicAdd(&h[dst[i] >> TSH], 1);
    __syncthreads();
    for (int i = threadIdx.x; i < nb; i += TPB)
        if (h[i]) atomicAdd(&bcnt[i], h[i]);
}

// single-block exclusive scan of bucket counts -> bstart, init bcursor
__global__ void k_bscan(const int* __restrict__ bcnt, int* __restrict__ bstart,
                        int* __restrict__ bcursor, int nb) {
    __shared__ int buf[2][MAXB];
    int t = threadIdx.x;            // 512 threads
    int v = (t < nb) ? bcnt[t] : 0;
    buf[0][t] = v;
    __syncthreads();
    int cur = 0;
#pragma unroll
    for (int off = 1; off < MAXB; off <<= 1) {
        int nv = buf[cur][t] + (t >= off ? buf[cur][t - off] : 0);
        buf[cur ^ 1][t] = nv;
        __syncthreads();
        cur ^= 1;
    }
    int excl = buf[cur][t] - v;
    if (t < nb) { bstart[t] = excl; bcursor[t] = excl; }
    if (t == nb - 1) bstart[nb] = excl + v;
}

// bucket scatter: contiguous runs into bedges, packed (local_dst<<18)|src
__global__ __launch_bounds__(1024) void k_bscatter(const int* __restrict__ src,
                                                   const int* __restrict__ dst,
                                                   int* __restrict__ bcursor,
                                                   uint32_t* __restrict__ bedges,
                                                   int e, int chunk) {
    __shared__ int hcnt[MAXB];
    __shared__ int hbase[MAXB];
    __shared__ int hpos[MAXB];
    int t = threadIdx.x;
    for (int i = t; i < MAXB; i += 1024) { hcnt[i] = 0; hpos[i] = 0; }
    __syncthreads();

    int e0 = blockIdx.x * chunk;
    int e1 = min(e0 + chunk, e);

    for (int i = e0 + t; i < e1; i += 1024)
        atomicAdd(&hcnt[dst[i] >> TSH], 1);
    __syncthreads();
    for (int i = t; i < MAXB; i += 1024)
        if (hcnt[i]) hbase[i] = atomicAdd(&bcursor[i], hcnt[i]);
    __syncthreads();
    for (int i = e0 + t; i < e1; i += 1024) {
        int d = dst[i];
        int b = d >> TSH;
        int lp = atomicAdd(&hpos[b], 1);
        bedges[hbase[b] + lp] = ((uint32_t)(d & (TILE - 1)) << 18) | (uint32_t)src[i];
    }
}

// per-bucket: counting-sort edges by src-tile (src>>SRCSH) -> bedges2,
// and in-degree hist over local_dst -> dis.
__global__ __launch_bounds__(1024) void k_tilesort(const uint32_t* __restrict__ bedges,
                                                   const int* __restrict__ bstart,
                                                   uint32_t* __restrict__ bedges2,
                                                   float* __restrict__ dis, int n) {
    __shared__ int th[32];
    __shared__ int tcur[32];
    __shared__ int dh[TILE];
    int t = threadIdx.x, b = blockIdx.x;
    int s0 = bstart[b], s1 = bstart[b + 1];

    if (t < 32) th[t] = 0;
    if (t < TILE) dh[t] = 0;
    __syncthreads();
    for (int i = s0 + t; i < s1; i += 1024) {
        uint32_t p = bedges[i];
        atomicAdd(&th[(p & 0x3FFFFu) >> SRCSH], 1);
        atomicAdd(&dh[p >> 18], 1);
    }
    __syncthreads();
    if (t == 0) {
        int run = 0;
#pragma unroll
        for (int i = 0; i < 32; ++i) { tcur[i] = run; run += th[i]; }
    }
    if (t < TILE) {
        int d = (b << TSH) + t;
        if (d < n) dis[d] = rsqrtf((float)dh[t] + 1.0f);
    }
    __syncthreads();
    for (int i = s0 + t; i < s1; i += 1024) {
        uint32_t p = bedges[i];
        int pos = atomicAdd(&tcur[(p & 0x3FFFFu) >> SRCSH], 1);
        bedges2[s0 + pos] = p;
    }
}

// h1w = fp16( (x @ W1) * dis[row] ).  W1 in LDS [k][lane]; 4 rows in flight.
__global__ __launch_bounds__(TPB) void k_gemm1h(const float* __restrict__ x,
                                                const float* __restrict__ W1,
                                                const float* __restrict__ dis,
                                                __half* __restrict__ h1w, int n) {
    __shared__ float w[128 * 32];
    for (int i = threadIdx.x; i < 128 * 32; i += TPB) w[i] = W1[i];
    __syncthreads();

    int lane = threadIdx.x & 31;
    int g    = threadIdx.x >> 5;
    int base = blockIdx.x * 64 + g * 8;

    for (int rb = 0; rb < 8; rb += 4) {
        int row = base + rb;
        if (row >= n) break;
        if (row + 3 < n) {
            const float4* x0 = (const float4*)(x + (size_t)row * 128);
            const float4* x1 = x0 + 32;
            const float4* x2 = x1 + 32;
            const float4* x3 = x2 + 32;
            float a0 = 0.f, a1 = 0.f, a2 = 0.f, a3 = 0.f;
#pragma unroll
            for (int k4 = 0; k4 < 32; ++k4) {
                float4 v0 = x0[k4], v1 = x1[k4], v2 = x2[k4], v3 = x3[k4];
                float w0 = w[(k4 * 4 + 0) * 32 + lane];
                float w1_ = w[(k4 * 4 + 1) * 32 + lane];
                float w2_ = w[(k4 * 4 + 2) * 32 + lane];
                float w3_ = w[(k4 * 4 + 3) * 32 + lane];
                a0 = fmaf(v0.x, w0, a0); a0 = fmaf(v0.y, w1_, a0);
                a0 = fmaf(v0.z, w2_, a0); a0 = fmaf(v0.w, w3_, a0);
                a1 = fmaf(v1.x, w0, a1); a1 = fmaf(v1.y, w1_, a1);
                a1 = fmaf(v1.z, w2_, a1); a1 = fmaf(v1.w, w3_, a1);
                a2 = fmaf(v2.x, w0, a2); a2 = fmaf(v2.y, w1_, a2);
                a2 = fmaf(v2.z, w2_, a2); a2 = fmaf(v2.w, w3_, a2);
                a3 = fmaf(v3.x, w0, a3); a3 = fmaf(v3.y, w1_, a3);
                a3 = fmaf(v3.z, w2_, a3); a3 = fmaf(v3.w, w3_, a3);
            }
            h1w[(size_t)(row + 0) * 32 + lane] = __float2half(a0 * dis[row + 0]);
            h1w[(size_t)(row + 1) * 32 + lane] = __float2half(a1 * dis[row + 1]);
            h1w[(size_t)(row + 2) * 32 + lane] = __float2half(a2 * dis[row + 2]);
            h1w[(size_t)(row + 3) * 32 + lane] = __float2half(a3 * dis[row + 3]);
        } else {
            for (int rr = 0; rr < 4; ++rr) {
                int rowi = row + rr;
                if (rowi >= n) break;
                const float4* x0 = (const float4*)(x + (size_t)rowi * 128);
                float a0 = 0.f;
#pragma unroll
                for (int k4 = 0; k4 < 32; ++k4) {
                    float4 v0 = x0[k4];
                    a0 = fmaf(v0.x, w[(k4 * 4 + 0) * 32 + lane], a0);
                    a0 = fmaf(v0.y, w[(k4 * 4 + 1) * 32 + lane], a0);
                    a0 = fmaf(v0.z, w[(k4 * 4 + 2) * 32 + lane], a0);
                    a0 = fmaf(v0.w, w[(k4 * 4 + 3) * 32 + lane], a0);
                }
                h1w[(size_t)rowi * 32 + lane] = __float2half(a0 * dis[rowi]);
            }
        }
    }
}

// Layer 1: per-bucket LDS accumulation over src-tile-sorted edges + fused
// self-loop/bias/relu/dropout/W2 epilogue -> hw2.
// 1024 thr = 16 waves; wave = 2 units of 32 lanes; unit handles one edge
// (lane = channel) -> ds_add_f32 conflict-free. 8 edges deep per unit.
__global__ __launch_bounds__(1024) void k_agg1(const uint32_t* __restrict__ bedges2,
                                               const int* __restrict__ bstart,
                                               const float* __restrict__ dis,
                                               const __half* __restrict__ h1w,
                                               const float* __restrict__ b1,
                                               const float* __restrict__ drop_u,
                                               const float* __restrict__ W2,
                                               float* __restrict__ hw2, int n) {
    __shared__ float acc[TILE * 32];   // 64 KB
    for (int i = threadIdx.x; i < TILE * 32; i += 1024) acc[i] = 0.0f;
    __syncthreads();

    int b  = blockIdx.x;
    int s0 = bstart[b], s1 = bstart[b + 1];
    int cnt = s1 - s0;

    int c    = threadIdx.x & 31;          // channel
    int unit = (threadIdx.x >> 5) & 1;    // edge parity within wave
    int wid  = threadIdx.x >> 6;          // wave id 0..15

    int nfull = cnt >> 4;                 // full 16-edge blocks
    for (int blk = wid; blk < nfull; blk += 16) {
        int base = s0 + (blk << 4) + unit;
        uint32_t p[8];
#pragma unroll
        for (int u = 0; u < 8; ++u)
            p[u] = bedges2[base + 2 * u];
        float v[8];
#pragma unroll
        for (int u = 0; u < 8; ++u)
            v[u] = __half2float(h1w[(size_t)(p[u] & 0x3FFFFu) * 32 + c]);
#pragma unroll
        for (int u = 0; u < 8; ++u)
            atomicAdd(&acc[(p[u] >> 18) * 32 + c], v[u]);
    }
    // tail: one edge per 32-lane unit
    for (int i = s0 + (nfull << 4) + (threadIdx.x >> 5); i < s1; i += 32) {
        uint32_t p = bedges2[i];
        atomicAdd(&acc[(p >> 18) * 32 + c], __half2float(h1w[(size_t)(p & 0x3FFFFu) * 32 + c]));
    }
    __syncthreads();

    // epilogue: 32 groups of 32 lanes sweep the 512 dst rows
    int g = threadIdx.x >> 5;
    int base_d = b << TSH;
    for (int ld = g; ld < TILE; ld += 32) {
        int d = base_d + ld;
        if (d >= n) continue;             // uniform within group
        float dd = dis[d];
        float v = dd * (acc[ld * 32 + c] + __half2float(h1w[(size_t)d * 32 + c])) + b1[c];
        v = fmaxf(v, 0.0f);
        v = (drop_u[(size_t)d * 32 + c] > 0.5f) ? v * 2.0f : 0.0f;
        float p0 = v * W2[c * 2 + 0];
        float p1 = v * W2[c * 2 + 1];
#pragma unroll
        for (int off = 16; off >= 1; off >>= 1) {
            p0 += __shfl_xor(p0, off, 32);
            p1 += __shfl_xor(p1, off, 32);
        }
        if (c == 0) {
            float2 o; o.x = p0 * dd; o.y = p1 * dd;
            ((float2*)hw2)[d] = o;
        }
    }
}

// Layer 2: per-bucket LDS accumulation over hw2 (1.6MB, L2-resident) -> out
__global__ __launch_bounds__(1024) void k_agg2(const uint32_t* __restrict__ bedges,
                                               const int* __restrict__ bstart,
                                               const float* __restrict__ dis,
                                               const float* __restrict__ hw2,
                                               const float* __restrict__ b2,
                                               float* __restrict__ out, int n) {
    __shared__ float acc2[TILE * 2];   // 4 KB
    int t = threadIdx.x;
    acc2[t] = 0.0f;                    // TILE*2 == 1024
    __syncthreads();

    int b  = blockIdx.x;
    int s0 = bstart[b], s1 = bstart[b + 1];
    for (int i = s0 + t; i < s1; i += 1024) {
        uint32_t p = bedges[i];
        int s  = (int)(p & 0x3FFFFu);
        int ld = (int)(p >> 18);
        float2 hv = ((const float2*)hw2)[s];
        atomicAdd(&acc2[ld * 2 + 0], hv.x);
        atomicAdd(&acc2[ld * 2 + 1], hv.y);
    }
    __syncthreads();

    int ld = t >> 1, j = t & 1;
    int d = (b << TSH) + ld;
    if (d < n) out[(size_t)d * 2 + j] = dis[d] * (acc2[t] + hw2[(size_t)d * 2 + j]) + b2[j];
}

extern "C" void kernel_launch(void* const* d_in, const int* in_sizes, int n_in,
                              void* d_out, int out_size, void* d_ws, size_t ws_size,
                              hipStream_t stream) {
    const float* x     = (const float*)d_in[0];
    const int*   ei    = (const int*)d_in[1];
    const float* W1    = (const float*)d_in[2];
    const float* b1    = (const float*)d_in[3];
    const float* W2    = (const float*)d_in[4];
    const float* b2    = (const float*)d_in[5];
    const float* dropu = (const float*)d_in[6];
    float* out = (float*)d_out;

    const int N = in_sizes[0] / 128;
    const int E = in_sizes[1] / 2;
    const int* src = ei;
    const int* dst = ei + E;

    const int NB = (N + TILE - 1) >> TSH;     // 391 for N=200000

    // ws: dis f32[N] | hw2 f32[2N] | bcnt i32[MAXB] | bstart i32[MAXB+1] |
    //     bcursor i32[MAXB] | bedges u32[E] | bedges2 u32[E] | h1w fp16[32N]
    float* dis = (float*)d_ws;
    float* hw2 = dis + N;
    int* bcnt    = (int*)(hw2 + (size_t)N * 2);
    int* bstart  = bcnt + MAXB;
    int* bcursor = bstart + (MAXB + 1);
    uint32_t* bedges  = (uint32_t*)(bcursor + MAXB);
    uint32_t* bedges2 = bedges + E;
    __half* h1w = (__half*)(bedges2 + E);

    const int chunk = (E + NB - 1) / NB;

    k_zero_i  <<<(MAXB + TPB - 1) / TPB, TPB, 0, stream>>>(bcnt, MAXB);
    k_bhist   <<<1024, TPB, 0, stream>>>(dst, bcnt, E, NB);
    k_bscan   <<<1, MAXB, 0, stream>>>(bcnt, bstart, bcursor, NB);
    k_bscatter<<<NB, 1024, 0, stream>>>(src, dst, bcursor, bedges, E, chunk);
    k_tilesort<<<NB, 1024, 0, stream>>>(bedges, bstart, bedges2, dis, N);
    k_gemm1h  <<<(N + 63) / 64, TPB, 0, stream>>>(x, W1, dis, h1w, N);
    k_agg1    <<<NB, 1024, 0, stream>>>(bedges2, bstart, dis, h1w, b1, dropu, W2, hw2, N);
    k_agg2    <<<NB, 1024, 0, stream>>>(bedges, bstart, dis, hw2, b2, out, N);
}

// Round 9
// 476.947 us; speedup vs baseline: 3.4885x; 3.4885x over previous
//
#include <hip/hip_runtime.h>
#include <hip/hip_fp16.h>
#include <stdint.h>

// GCN 2-layer forward: two-level counting sort -> dst-sorted CSR -> pull gathers.
// h1w fp16. GEMM v3: x-tile staged in LDS (coalesced), compute from LDS broadcasts.
// bhist chunk-aligned with bscatter, spills per-block hist to global (hall).

#define TPB 256
#define TILE 512           // nodes per bucket
#define TSH  9
#define MAXB 512           // supports N <= 262144 (src must fit 18 bits)

__global__ void k_zero_i(int* __restrict__ p, int m) {
    int i = blockIdx.x * TPB + threadIdx.x;
    if (i < m) p[i] = 0;
}

// chunked per-bucket histogram; spills per-block counts to hall and sums bcnt.
__global__ __launch_bounds__(1024) void k_bhist(const int* __restrict__ dst,
                                                int* __restrict__ bcnt,
                                                int* __restrict__ hall,
                                                int e, int chunk, int nb) {
    __shared__ int h[MAXB];
    int t = threadIdx.x, b = blockIdx.x;
    for (int i = t; i < MAXB; i += 1024) h[i] = 0;
    __syncthreads();
    int e0 = b * chunk, e1 = min(e0 + chunk, e);
    for (int i = e0 + t; i < e1; i += 1024)
        atomicAdd(&h[dst[i] >> TSH], 1);
    __syncthreads();
    for (int i = t; i < nb; i += 1024) {
        int c = h[i];
        hall[(size_t)b * MAXB + i] = c;
        if (c) atomicAdd(&bcnt[i], c);
    }
}

// single-block exclusive scan of bucket counts -> bstart, init bcursor
__global__ void k_bscan(const int* __restrict__ bcnt, int* __restrict__ bstart,
                        int* __restrict__ bcursor, int nb) {
    __shared__ int buf[2][MAXB];
    int t = threadIdx.x;            // 512 threads
    int v = (t < nb) ? bcnt[t] : 0;
    buf[0][t] = v;
    __syncthreads();
    int cur = 0;
#pragma unroll
    for (int off = 1; off < MAXB; off <<= 1) {
        int nv = buf[cur][t] + (t >= off ? buf[cur][t - off] : 0);
        buf[cur ^ 1][t] = nv;
        __syncthreads();
        cur ^= 1;
    }
    int excl = buf[cur][t] - v;
    if (t < nb) { bstart[t] = excl; bcursor[t] = excl; }
    if (t == nb - 1) bstart[nb] = excl + v;
}

// bucket scatter using precomputed per-block counts (hall): one pass over edges.
__global__ __launch_bounds__(1024) void k_bscatter(const int* __restrict__ src,
                                                   const int* __restrict__ dst,
                                                   const int* __restrict__ hall,
                                                   int* __restrict__ bcursor,
                                                   uint32_t* __restrict__ bedges,
                                                   int e, int chunk, int nb) {
    __shared__ int hbase[MAXB];
    __shared__ int hpos[MAXB];
    int t = threadIdx.x, b = blockIdx.x;
    for (int i = t; i < nb; i += 1024) {
        int c = hall[(size_t)b * MAXB + i];
        hpos[i] = 0;
        hbase[i] = c ? atomicAdd(&bcursor[i], c) : 0;
    }
    __syncthreads();
    int e0 = b * chunk, e1 = min(e0 + chunk, e);
    for (int i = e0 + t; i < e1; i += 1024) {
        int d = dst[i];
        int bb = d >> TSH;
        int lp = atomicAdd(&hpos[bb], 1);
        bedges[hbase[bb] + lp] = ((uint32_t)(d & (TILE - 1)) << 18) | (uint32_t)src[i];
    }
}

// per-bucket counting sort: bedges segment -> csr (src only, exact dst order).
// Also emits node_start[d] and dis[d].
__global__ __launch_bounds__(1024) void k_sort(const uint32_t* __restrict__ bedges,
                                               const int* __restrict__ bstart,
                                               uint32_t* __restrict__ csr,
                                               int* __restrict__ node_start,
                                               float* __restrict__ dis, int n) {
    __shared__ int hist[TILE];
    __shared__ int sb[2][TILE];
    __shared__ int curp[TILE];
    int t = threadIdx.x;            // 1024 threads
    int b = blockIdx.x;
    int s0 = bstart[b], s1 = bstart[b + 1];

    if (t < TILE) hist[t] = 0;
    __syncthreads();
    for (int i = s0 + t; i < s1; i += 1024)
        atomicAdd(&hist[bedges[i] >> 18], 1);
    __syncthreads();

    if (t < TILE) sb[0][t] = hist[t];
    __syncthreads();
    int cur = 0;
#pragma unroll
    for (int off = 1; off < TILE; off <<= 1) {
        if (t < TILE) {
            int nv = sb[cur][t] + (t >= off ? sb[cur][t - off] : 0);
            sb[cur ^ 1][t] = nv;
        }
        __syncthreads();
        cur ^= 1;
    }
    if (t < TILE) {
        int ex = sb[cur][t] - hist[t];          // exclusive
        curp[t] = ex;
        int d = (b << TSH) + t;
        if (d <= n) node_start[d] = s0 + ex;
        if (d < n)  dis[d] = rsqrtf((float)hist[t] + 1.0f);
    }
    __syncthreads();

    for (int i = s0 + t; i < s1; i += 1024) {
        uint32_t p = bedges[i];
        int ld = (int)(p >> 18);
        int pos = atomicAdd(&curp[ld], 1);
        csr[s0 + pos] = p & 0x3FFFFu;
    }
}

// h1w = fp16( (x @ W1) * dis[row] ).  GEMM v3:
// x-tile (64 rows x 128) staged in LDS via coalesced float4 loads (32 VMEM/64 rows
// vs 512 broadcast VMEM before). W1 in LDS [k][c]. 8 groups x 8 rows; per k4 per
// 4-row batch: 4 uniform ds_read_b128 (x) + 4 ds_read_b32 (w) feed 16 FMAs.
__global__ __launch_bounds__(TPB) void k_gemm1h(const float* __restrict__ x,
                                                const float* __restrict__ W1,
                                                const float* __restrict__ dis,
                                                __half* __restrict__ h1w, int n) {
    __shared__ float w[128 * 32];    // 16 KB
    __shared__ float xt[64 * 128];   // 32 KB
    int t = threadIdx.x;
    for (int i = t; i < 128 * 32; i += TPB) w[i] = W1[i];

    int row0 = blockIdx.x * 64;
    int nrow = min(64, n - row0);
    {
        const float4* xg = (const float4*)(x + (size_t)row0 * 128);
        float4* xs = (float4*)xt;
        int nf4 = nrow * 32;
        for (int i = t; i < nf4; i += TPB) xs[i] = xg[i];
    }
    __syncthreads();

    int lane = t & 31;
    int g    = t >> 5;          // 8 groups x 8 rows = 64 rows
    int rbase = g * 8;

    for (int rb = 0; rb < 8; rb += 4) {
        int lr = rbase + rb;
        if (row0 + lr >= n) break;
        const float4* xr0 = (const float4*)&xt[(lr + 0) * 128];
        const float4* xr1 = (const float4*)&xt[(lr + 1) * 128];
        const float4* xr2 = (const float4*)&xt[(lr + 2) * 128];
        const float4* xr3 = (const float4*)&xt[(lr + 3) * 128];
        float a0 = 0.f, a1 = 0.f, a2 = 0.f, a3 = 0.f;
#pragma unroll
        for (int k4 = 0; k4 < 32; ++k4) {
            float4 v0 = xr0[k4], v1 = xr1[k4], v2 = xr2[k4], v3 = xr3[k4];
            float w0 = w[(k4 * 4 + 0) * 32 + lane];
            float w1_ = w[(k4 * 4 + 1) * 32 + lane];
            float w2_ = w[(k4 * 4 + 2) * 32 + lane];
            float w3_ = w[(k4 * 4 + 3) * 32 + lane];
            a0 = fmaf(v0.x, w0, a0); a0 = fmaf(v0.y, w1_, a0);
            a0 = fmaf(v0.z, w2_, a0); a0 = fmaf(v0.w, w3_, a0);
            a1 = fmaf(v1.x, w0, a1); a1 = fmaf(v1.y, w1_, a1);
            a1 = fmaf(v1.z, w2_, a1); a1 = fmaf(v1.w, w3_, a1);
            a2 = fmaf(v2.x, w0, a2); a2 = fmaf(v2.y, w1_, a2);
            a2 = fmaf(v2.z, w2_, a2); a2 = fmaf(v2.w, w3_, a2);
            a3 = fmaf(v3.x, w0, a3); a3 = fmaf(v3.y, w1_, a3);
            a3 = fmaf(v3.z, w2_, a3); a3 = fmaf(v3.w, w3_, a3);
        }
        int r0 = row0 + lr;
        if (r0 + 0 < n) h1w[(size_t)(r0 + 0) * 32 + lane] = __float2half(a0 * dis[r0 + 0]);
        if (r0 + 1 < n) h1w[(size_t)(r0 + 1) * 32 + lane] = __float2half(a1 * dis[r0 + 1]);
        if (r0 + 2 < n) h1w[(size_t)(r0 + 2) * 32 + lane] = __float2half(a2 * dis[r0 + 2]);
        if (r0 + 3 < n) h1w[(size_t)(r0 + 3) * 32 + lane] = __float2half(a3 * dis[r0 + 3]);
    }
}

// Layer1 gather (fp16 rows) + fused self-loop/bias/relu/dropout/W2; hw2=(v@W2)*dis[d]
__global__ __launch_bounds__(TPB) void k_gather1(const int* __restrict__ node_start,
                                                 const uint32_t* __restrict__ csr,
                                                 const float* __restrict__ dis,
                                                 const __half* __restrict__ h1w,
                                                 const float* __restrict__ b1,
                                                 const float* __restrict__ drop_u,
                                                 const float* __restrict__ W2,
                                                 float* __restrict__ hw2, int n) {
    int t = blockIdx.x * TPB + threadIdx.x;
    int d = t >> 5, c = t & 31;
    if (d >= n) return;

    int e  = node_start[d];
    int e1 = node_start[d + 1];

    float acc = 0.0f;
    for (; e + 7 < e1; e += 8) {
        int s0 = csr[e],     s1 = csr[e + 1], s2 = csr[e + 2], s3 = csr[e + 3];
        int s4 = csr[e + 4], s5 = csr[e + 5], s6 = csr[e + 6], s7 = csr[e + 7];
        float v0 = __half2float(h1w[(size_t)s0 * 32 + c]);
        float v1 = __half2float(h1w[(size_t)s1 * 32 + c]);
        float v2 = __half2float(h1w[(size_t)s2 * 32 + c]);
        float v3 = __half2float(h1w[(size_t)s3 * 32 + c]);
        float v4 = __half2float(h1w[(size_t)s4 * 32 + c]);
        float v5 = __half2float(h1w[(size_t)s5 * 32 + c]);
        float v6 = __half2float(h1w[(size_t)s6 * 32 + c]);
        float v7 = __half2float(h1w[(size_t)s7 * 32 + c]);
        acc += ((v0 + v1) + (v2 + v3)) + ((v4 + v5) + (v6 + v7));
    }
    for (; e < e1; ++e) acc += __half2float(h1w[(size_t)csr[e] * 32 + c]);

    float dd = dis[d];
    float selfv = __half2float(h1w[(size_t)d * 32 + c]);
    float v = dd * (acc + selfv) + b1[c];
    v = fmaxf(v, 0.0f);
    v = (drop_u[(size_t)d * 32 + c] > 0.5f) ? v * 2.0f : 0.0f;

    float p0 = v * W2[c * 2 + 0];
    float p1 = v * W2[c * 2 + 1];
#pragma unroll
    for (int off = 16; off >= 1; off >>= 1) {
        p0 += __shfl_xor(p0, off, 32);
        p1 += __shfl_xor(p1, off, 32);
    }
    if (c == 0) {
        float2 o; o.x = p0 * dd; o.y = p1 * dd;
        ((float2*)hw2)[d] = o;
    }
}

// Layer2 gather: out[d] = dis[d]*(sum_s hw2[s] + hw2[d]) + b2
__global__ __launch_bounds__(TPB) void k_gather2(const int* __restrict__ node_start,
                                                 const uint32_t* __restrict__ csr,
                                                 const float* __restrict__ dis,
                                                 const float* __restrict__ hw2,
                                                 const float* __restrict__ b2,
                                                 float* __restrict__ out, int n) {
    int t = blockIdx.x * TPB + threadIdx.x;
    int d = t >> 5, lane = t & 31;
    if (d >= n) return;

    int e0 = node_start[d];
    int e1 = node_start[d + 1];

    float a0 = 0.0f, a1 = 0.0f;
    for (int e = e0 + lane; e < e1; e += 32) {
        int s = csr[e];
        float2 hv = ((const float2*)hw2)[s];
        a0 += hv.x;
        a1 += hv.y;
    }
#pragma unroll
    for (int off = 16; off >= 1; off >>= 1) {
        a0 += __shfl_xor(a0, off, 32);
        a1 += __shfl_xor(a1, off, 32);
    }
    if (lane == 0) {
        float dd = dis[d];
        float2 hv = ((const float2*)hw2)[d];
        out[(size_t)d * 2 + 0] = dd * (a0 + hv.x) + b2[0];
        out[(size_t)d * 2 + 1] = dd * (a1 + hv.y) + b2[1];
    }
}

extern "C" void kernel_launch(void* const* d_in, const int* in_sizes, int n_in,
                              void* d_out, int out_size, void* d_ws, size_t ws_size,
                              hipStream_t stream) {
    const float* x     = (const float*)d_in[0];
    const int*   ei    = (const int*)d_in[1];
    const float* W1    = (const float*)d_in[2];
    const float* b1    = (const float*)d_in[3];
    const float* W2    = (const float*)d_in[4];
    const float* b2    = (const float*)d_in[5];
    const float* dropu = (const float*)d_in[6];
    float* out = (float*)d_out;

    const int N = in_sizes[0] / 128;
    const int E = in_sizes[1] / 2;
    const int* src = ei;
    const int* dst = ei + E;

    const int NB = (N + TILE - 1) >> TSH;     // 391 for N=200000

    // ws: dis f32[N] | hw2 f32[2N] | node_start i32[N+1] | bcnt i32[MAXB] |
    //     bstart i32[MAXB+1] | bcursor i32[MAXB] | hall i32[MAXB*MAXB] |
    //     bedges u32[E] | csr u32[E] | h1w fp16[32N]
    float* dis = (float*)d_ws;
    float* hw2 = dis + N;
    int* node_start = (int*)(hw2 + (size_t)N * 2);
    int* bcnt    = node_start + (N + 1);
    int* bstart  = bcnt + MAXB;
    int* bcursor = bstart + (MAXB + 1);
    int* hall    = bcursor + MAXB;
    uint32_t* bedges = (uint32_t*)(hall + (size_t)MAXB * MAXB);
    uint32_t* csr    = bedges + E;
    __half* h1w = (__half*)(csr + E);

    const int chunk = (E + NB - 1) / NB;
    const int gG = (N * 32 + TPB - 1) / TPB;  // 32 lanes per node

    k_zero_i  <<<(MAXB + TPB - 1) / TPB, TPB, 0, stream>>>(bcnt, MAXB);
    k_bhist   <<<NB, 1024, 0, stream>>>(dst, bcnt, hall, E, chunk, NB);
    k_bscan   <<<1, MAXB, 0, stream>>>(bcnt, bstart, bcursor, NB);
    k_bscatter<<<NB, 1024, 0, stream>>>(src, dst, hall, bcursor, bedges, E, chunk, NB);
    k_sort    <<<NB, 1024, 0, stream>>>(bedges, bstart, csr, node_start, dis, N);
    k_gemm1h  <<<(N + 63) / 64, TPB, 0, stream>>>(x, W1, dis, h1w, N);
    k_gather1 <<<gG, TPB, 0, stream>>>(node_start, csr, dis, h1w, b1, dropu, W2, hw2, N);
    k_gather2 <<<gG, TPB, 0, stream>>>(node_start, csr, dis, hw2, b2, out, N);
}

// Round 10
// 343.911 us; speedup vs baseline: 4.8379x; 1.3868x over previous
//
#include <hip/hip_runtime.h>
#include <hip/hip_fp16.h>
#include <stdint.h>

// GCN 2-layer forward: two-level counting sort -> dst-sorted CSR -> pull gathers.
// h1w fp16. GEMM now uses MFMA (mfma_f32_16x16x32_f16): M=200k,K=128,N=32.
// k-placement into A/B fragments uses a consistent bijection (8*(lane>>4)+e)
// for both operands -> contraction invariant to HW k-order. C: col=lane&15,
// row=4*(lane>>4)+reg (learn_hip m89).

#define TPB 256
#define TILE 512           // nodes per bucket
#define TSH  9
#define MAXB 512           // supports N <= 262144 (src must fit 18 bits)

typedef _Float16 f16x8 __attribute__((ext_vector_type(8)));
typedef float    f32x4 __attribute__((ext_vector_type(4)));

__global__ void k_zero_i(int* __restrict__ p, int m) {
    int i = blockIdx.x * TPB + threadIdx.x;
    if (i < m) p[i] = 0;
}

// chunked per-bucket histogram; spills per-block counts to hall and sums bcnt.
__global__ __launch_bounds__(1024) void k_bhist(const int* __restrict__ dst,
                                                int* __restrict__ bcnt,
                                                int* __restrict__ hall,
                                                int e, int chunk, int nb) {
    __shared__ int h[MAXB];
    int t = threadIdx.x, b = blockIdx.x;
    for (int i = t; i < MAXB; i += 1024) h[i] = 0;
    __syncthreads();
    int e0 = b * chunk, e1 = min(e0 + chunk, e);
    for (int i = e0 + t; i < e1; i += 1024)
        atomicAdd(&h[dst[i] >> TSH], 1);
    __syncthreads();
    for (int i = t; i < nb; i += 1024) {
        int c = h[i];
        hall[(size_t)b * MAXB + i] = c;
        if (c) atomicAdd(&bcnt[i], c);
    }
}

// single-block exclusive scan of bucket counts -> bstart, init bcursor
__global__ void k_bscan(const int* __restrict__ bcnt, int* __restrict__ bstart,
                        int* __restrict__ bcursor, int nb) {
    __shared__ int buf[2][MAXB];
    int t = threadIdx.x;            // 512 threads
    int v = (t < nb) ? bcnt[t] : 0;
    buf[0][t] = v;
    __syncthreads();
    int cur = 0;
#pragma unroll
    for (int off = 1; off < MAXB; off <<= 1) {
        int nv = buf[cur][t] + (t >= off ? buf[cur][t - off] : 0);
        buf[cur ^ 1][t] = nv;
        __syncthreads();
        cur ^= 1;
    }
    int excl = buf[cur][t] - v;
    if (t < nb) { bstart[t] = excl; bcursor[t] = excl; }
    if (t == nb - 1) bstart[nb] = excl + v;
}

// bucket scatter using precomputed per-block counts (hall): one pass over edges.
__global__ __launch_bounds__(1024) void k_bscatter(const int* __restrict__ src,
                                                   const int* __restrict__ dst,
                                                   const int* __restrict__ hall,
                                                   int* __restrict__ bcursor,
                                                   uint32_t* __restrict__ bedges,
                                                   int e, int chunk, int nb) {
    __shared__ int hbase[MAXB];
    __shared__ int hpos[MAXB];
    int t = threadIdx.x, b = blockIdx.x;
    for (int i = t; i < nb; i += 1024) {
        int c = hall[(size_t)b * MAXB + i];
        hpos[i] = 0;
        hbase[i] = c ? atomicAdd(&bcursor[i], c) : 0;
    }
    __syncthreads();
    int e0 = b * chunk, e1 = min(e0 + chunk, e);
    for (int i = e0 + t; i < e1; i += 1024) {
        int d = dst[i];
        int bb = d >> TSH;
        int lp = atomicAdd(&hpos[bb], 1);
        bedges[hbase[bb] + lp] = ((uint32_t)(d & (TILE - 1)) << 18) | (uint32_t)src[i];
    }
}

// per-bucket counting sort: bedges segment -> csr (src only, exact dst order).
// Also emits node_start[d] and dis[d].
__global__ __launch_bounds__(1024) void k_sort(const uint32_t* __restrict__ bedges,
                                               const int* __restrict__ bstart,
                                               uint32_t* __restrict__ csr,
                                               int* __restrict__ node_start,
                                               float* __restrict__ dis, int n) {
    __shared__ int hist[TILE];
    __shared__ int sb[2][TILE];
    __shared__ int curp[TILE];
    int t = threadIdx.x;            // 1024 threads
    int b = blockIdx.x;
    int s0 = bstart[b], s1 = bstart[b + 1];

    if (t < TILE) hist[t] = 0;
    __syncthreads();
    for (int i = s0 + t; i < s1; i += 1024)
        atomicAdd(&hist[bedges[i] >> 18], 1);
    __syncthreads();

    if (t < TILE) sb[0][t] = hist[t];
    __syncthreads();
    int cur = 0;
#pragma unroll
    for (int off = 1; off < TILE; off <<= 1) {
        if (t < TILE) {
            int nv = sb[cur][t] + (t >= off ? sb[cur][t - off] : 0);
            sb[cur ^ 1][t] = nv;
        }
        __syncthreads();
        cur ^= 1;
    }
    if (t < TILE) {
        int ex = sb[cur][t] - hist[t];          // exclusive
        curp[t] = ex;
        int d = (b << TSH) + t;
        if (d <= n) node_start[d] = s0 + ex;
        if (d < n)  dis[d] = rsqrtf((float)hist[t] + 1.0f);
    }
    __syncthreads();

    for (int i = s0 + t; i < s1; i += 1024) {
        uint32_t p = bedges[i];
        int ld = (int)(p >> 18);
        int pos = atomicAdd(&curp[ld], 1);
        csr[s0 + pos] = p & 0x3FFFFu;
    }
}

// h1w = fp16( (x @ W1) * dis[row] ) via MFMA.
// One wave per 16-row tile: 4 k-steps x 2 N-tiles of mfma_f32_16x16x32_f16.
// A slot (g=lane>>4, e): x[tile*16 + (lane&15)][32*s + 8*g + e]
// B slot (g, e):         W1[32*s + 8*g + e][16*t + (lane&15)]
// C: col=lane&15 (channel within N-tile), row=tile*16 + 4*g + i.
__global__ __launch_bounds__(TPB) void k_gemm_mfma(const float* __restrict__ x,
                                                   const float* __restrict__ W1,
                                                   const float* __restrict__ dis,
                                                   __half* __restrict__ h1w, int n) {
    int l   = threadIdx.x & 63;
    int wid = threadIdx.x >> 6;      // wave 0..3
    int lg  = l >> 4;                // 0..3
    int ln  = l & 15;

    // preload B fragments (64 halves = 32 VGPR)
    f16x8 bf[4][2];
#pragma unroll
    for (int s = 0; s < 4; ++s)
#pragma unroll
        for (int t = 0; t < 2; ++t)
#pragma unroll
            for (int e = 0; e < 8; ++e)
                bf[s][t][e] = (_Float16)W1[(32 * s + 8 * lg + e) * 32 + 16 * t + ln];

    int ntiles = (n + 15) >> 4;
    int stride = gridDim.x * 4;
    for (int tile = blockIdx.x * 4 + wid; tile < ntiles; tile += stride) {
        int row = (tile << 4) + ln;          // A-row this lane supplies
        bool rv = row < n;
        const float* xr = x + (size_t)row * 128 + 8 * lg;

        f32x4 acc0 = {0.f, 0.f, 0.f, 0.f};
        f32x4 acc1 = {0.f, 0.f, 0.f, 0.f};
#pragma unroll
        for (int s = 0; s < 4; ++s) {
            float4 lo, hi;
            if (rv) {
                lo = *(const float4*)(xr + 32 * s);
                hi = *(const float4*)(xr + 32 * s + 4);
            } else {
                lo = make_float4(0.f, 0.f, 0.f, 0.f);
                hi = lo;
            }
            f16x8 a;
            a[0] = (_Float16)lo.x; a[1] = (_Float16)lo.y;
            a[2] = (_Float16)lo.z; a[3] = (_Float16)lo.w;
            a[4] = (_Float16)hi.x; a[5] = (_Float16)hi.y;
            a[6] = (_Float16)hi.z; a[7] = (_Float16)hi.w;
            acc0 = __builtin_amdgcn_mfma_f32_16x16x32_f16(a, bf[s][0], acc0, 0, 0, 0);
            acc1 = __builtin_amdgcn_mfma_f32_16x16x32_f16(a, bf[s][1], acc1, 0, 0, 0);
        }

        int trow = tile << 4;
#pragma unroll
        for (int i = 0; i < 4; ++i) {
            int rowc = trow + 4 * lg + i;
            if (rowc < n) {
                float dd = dis[rowc];
                h1w[(size_t)rowc * 32 + ln]      = __float2half(acc0[i] * dd);
                h1w[(size_t)rowc * 32 + 16 + ln] = __float2half(acc1[i] * dd);
            }
        }
    }
}

// Layer1 gather (fp16 rows) + fused self-loop/bias/relu/dropout/W2; hw2=(v@W2)*dis[d]
__global__ __launch_bounds__(TPB) void k_gather1(const int* __restrict__ node_start,
                                                 const uint32_t* __restrict__ csr,
                                                 const float* __restrict__ dis,
                                                 const __half* __restrict__ h1w,
                                                 const float* __restrict__ b1,
                                                 const float* __restrict__ drop_u,
                                                 const float* __restrict__ W2,
                                                 float* __restrict__ hw2, int n) {
    int t = blockIdx.x * TPB + threadIdx.x;
    int d = t >> 5, c = t & 31;
    if (d >= n) return;

    int e  = node_start[d];
    int e1 = node_start[d + 1];

    float acc = 0.0f;
    for (; e + 7 < e1; e += 8) {
        int s0 = csr[e],     s1 = csr[e + 1], s2 = csr[e + 2], s3 = csr[e + 3];
        int s4 = csr[e + 4], s5 = csr[e + 5], s6 = csr[e + 6], s7 = csr[e + 7];
        float v0 = __half2float(h1w[(size_t)s0 * 32 + c]);
        float v1 = __half2float(h1w[(size_t)s1 * 32 + c]);
        float v2 = __half2float(h1w[(size_t)s2 * 32 + c]);
        float v3 = __half2float(h1w[(size_t)s3 * 32 + c]);
        float v4 = __half2float(h1w[(size_t)s4 * 32 + c]);
        float v5 = __half2float(h1w[(size_t)s5 * 32 + c]);
        float v6 = __half2float(h1w[(size_t)s6 * 32 + c]);
        float v7 = __half2float(h1w[(size_t)s7 * 32 + c]);
        acc += ((v0 + v1) + (v2 + v3)) + ((v4 + v5) + (v6 + v7));
    }
    for (; e < e1; ++e) acc += __half2float(h1w[(size_t)csr[e] * 32 + c]);

    float dd = dis[d];
    float selfv = __half2float(h1w[(size_t)d * 32 + c]);
    float v = dd * (acc + selfv) + b1[c];
    v = fmaxf(v, 0.0f);
    v = (drop_u[(size_t)d * 32 + c] > 0.5f) ? v * 2.0f : 0.0f;

    float p0 = v * W2[c * 2 + 0];
    float p1 = v * W2[c * 2 + 1];
#pragma unroll
    for (int off = 16; off >= 1; off >>= 1) {
        p0 += __shfl_xor(p0, off, 32);
        p1 += __shfl_xor(p1, off, 32);
    }
    if (c == 0) {
        float2 o; o.x = p0 * dd; o.y = p1 * dd;
        ((float2*)hw2)[d] = o;
    }
}

// Layer2 gather: out[d] = dis[d]*(sum_s hw2[s] + hw2[d]) + b2
__global__ __launch_bounds__(TPB) void k_gather2(const int* __restrict__ node_start,
                                                 const uint32_t* __restrict__ csr,
                                                 const float* __restrict__ dis,
                                                 const float* __restrict__ hw2,
                                                 const float* __restrict__ b2,
                                                 float* __restrict__ out, int n) {
    int t = blockIdx.x * TPB + threadIdx.x;
    int d = t >> 5, lane = t & 31;
    if (d >= n) return;

    int e0 = node_start[d];
    int e1 = node_start[d + 1];

    float a0 = 0.0f, a1 = 0.0f;
    for (int e = e0 + lane; e < e1; e += 32) {
        int s = csr[e];
        float2 hv = ((const float2*)hw2)[s];
        a0 += hv.x;
        a1 += hv.y;
    }
#pragma unroll
    for (int off = 16; off >= 1; off >>= 1) {
        a0 += __shfl_xor(a0, off, 32);
        a1 += __shfl_xor(a1, off, 32);
    }
    if (lane == 0) {
        float dd = dis[d];
        float2 hv = ((const float2*)hw2)[d];
        out[(size_t)d * 2 + 0] = dd * (a0 + hv.x) + b2[0];
        out[(size_t)d * 2 + 1] = dd * (a1 + hv.y) + b2[1];
    }
}

extern "C" void kernel_launch(void* const* d_in, const int* in_sizes, int n_in,
                              void* d_out, int out_size, void* d_ws, size_t ws_size,
                              hipStream_t stream) {
    const float* x     = (const float*)d_in[0];
    const int*   ei    = (const int*)d_in[1];
    const float* W1    = (const float*)d_in[2];
    const float* b1    = (const float*)d_in[3];
    const float* W2    = (const float*)d_in[4];
    const float* b2    = (const float*)d_in[5];
    const float* dropu = (const float*)d_in[6];
    float* out = (float*)d_out;

    const int N = in_sizes[0] / 128;
    const int E = in_sizes[1] / 2;
    const int* src = ei;
    const int* dst = ei + E;

    const int NB = (N + TILE - 1) >> TSH;     // 391 for N=200000

    // ws: dis f32[N] | hw2 f32[2N] | node_start i32[N+1] | bcnt i32[MAXB] |
    //     bstart i32[MAXB+1] | bcursor i32[MAXB] | hall i32[MAXB*MAXB] |
    //     bedges u32[E] | csr u32[E] | h1w fp16[32N]
    float* dis = (float*)d_ws;
    float* hw2 = dis + N;
    int* node_start = (int*)(hw2 + (size_t)N * 2);
    int* bcnt    = node_start + (N + 1);
    int* bstart  = bcnt + MAXB;
    int* bcursor = bstart + (MAXB + 1);
    int* hall    = bcursor + MAXB;
    uint32_t* bedges = (uint32_t*)(hall + (size_t)MAXB * MAXB);
    uint32_t* csr    = bedges + E;
    __half* h1w = (__half*)(csr + E);

    const int chunk = (E + NB - 1) / NB;
    const int gG = (N * 32 + TPB - 1) / TPB;  // 32 lanes per node
    const int ntiles = (N + 15) >> 4;
    const int gT = (ntiles + 3) / 4;          // 4 waves (tiles) per block

    k_zero_i   <<<(MAXB + TPB - 1) / TPB, TPB, 0, stream>>>(bcnt, MAXB);
    k_bhist    <<<NB, 1024, 0, stream>>>(dst, bcnt, hall, E, chunk, NB);
    k_bscan    <<<1, MAXB, 0, stream>>>(bcnt, bstart, bcursor, NB);
    k_bscatter <<<NB, 1024, 0, stream>>>(src, dst, hall, bcursor, bedges, E, chunk, NB);
    k_sort     <<<NB, 1024, 0, stream>>>(bedges, bstart, csr, node_start, dis, N);
    k_gemm_mfma<<<gT, TPB, 0, stream>>>(x, W1, dis, h1w, N);
    k_gather1  <<<gG, TPB, 0, stream>>>(node_start, csr, dis, h1w, b1, dropu, W2, hw2, N);
    k_gather2  <<<gG, TPB, 0, stream>>>(node_start, csr, dis, hw2, b2, out, N);
}